// Round 5
// baseline (160.987 us; speedup 1.0000x reference)
//
#include <hip/hip_runtime.h>
#include <cstdint>
#include <cstddef>

#define T_LEN 4096
#define S_DIM 308
#define E_DIM 126
#define NBATCH 32
#define CHL 16                     // chunk length: 256 chunks, 2 per block (skewed)
#define NCH (T_LEN / CHL)          // 256
#define WARM 6                     // contraction ~0.066/step -> ~1e-6 relative after warm-up
#define NSTEP (CHL + WARM - 1)     // 21, uniform for ALL chunks (c==0 uses reset-at-IW)
#define IW (WARM - 1)              // checkpoint substep (z at t = c*CHL-1)
#define QROW 720                   // QL row stride BYTES = 180 dw == 20 (mod 32):
                                   //   b128 reads 8/bank, b64 writes 4/bank = conflict-free
#define TC 16                      // emis_pack timesteps per block
#define ROWB 20480                 // Efrag row bytes: 40 tiles * 64 lanes * 8B
#define LN128 4.852030263919617f   // ln(128): per-step prescale to telescope out

typedef _Float16 half8 __attribute__((ext_vector_type(8)));
typedef _Float16 half4 __attribute__((ext_vector_type(4)));
typedef float floatx4 __attribute__((ext_vector_type(4)));

union HU8 { uint4 u; half8 h; };
union HU4 { uint2 u; half4 h; };
union HU1 { uint16_t u; _Float16 h; };

__device__ __forceinline__ half8 h8_from_u4(uint4 v) { HU8 t; t.u = v; return t.h; }
__device__ __forceinline__ half4 h4_from_u2(uint2 v) { HU4 t; t.u = v; return t.h; }
__device__ __forceinline__ uint32_t pk2(float x, float y) {
  HU1 a, b; a.h = (_Float16)x; b.h = (_Float16)y;
  return (uint32_t)a.u | ((uint32_t)b.u << 16);
}

// LDS-only barrier: drain DS ops (ds_write/ds_read/LDS-atomics, both hazard
// directions) then raw s_barrier. Crucially does NOT drain vmcnt, so the
// in-flight Efrag/inp global loads (consumed from registers intervals later,
// compiler-tracked via its own vmcnt waits) stay in flight across the barrier.
// __syncthreads() would emit s_waitcnt vmcnt(0) and expose ~full L3/HBM
// latency every interval -- the measured ~2600-cycle/barrier constant.
__device__ __forceinline__ void bar_lds() {
  asm volatile("s_waitcnt lgkmcnt(0)" ::: "memory");
  __builtin_amdgcn_s_barrier();
}

// ---- merged init: blocks 0..49 pack A-frags, 50..69 pack B-frags, 70 zeroes out ----
// A-frag: tile = nt*10 + kt; lane l holds A[k=kt*32+(l>>4)*8+j][n=nt*16+(l&15)], j=0..7.
// Serves as MFMA A-operand for P^T = A^T @ Q^T (m = out-state, k = in-state).
// B-frag: tile = nt*4 + kt over E padded to 128, value = 128*B[n][k]; MFMA A-operand
// for E^T = (128*Bmat) @ inp^T in emis_pack. x128 telescopes into the loglik.
__global__ __launch_bounds__(256) void init_pack(const float* __restrict__ A,
                                                 const float* __restrict__ Bm,
                                                 uint32_t* __restrict__ Apk,
                                                 uint32_t* __restrict__ Bfr,
                                                 float* __restrict__ out) {
  int blk = blockIdx.x, tid = threadIdx.x;
  if (blk < 50) {
    int idx = blk * 256 + tid;                 // 200 tiles * 64 lanes
    int lane = idx & 63, tile = idx >> 6;
    int kt = tile % 10, nt = tile / 10;
    int n  = nt * 16 + (lane & 15);
    int k0 = kt * 32 + (lane >> 4) * 8;
    uint32_t wv[4];
#pragma unroll
    for (int jj = 0; jj < 4; jj++) {
      int ka = k0 + 2 * jj, kb = ka + 1;
      float x0 = (n < S_DIM && ka < S_DIM) ? A[ka * S_DIM + n] : 0.f;
      float x1 = (n < S_DIM && kb < S_DIM) ? A[kb * S_DIM + n] : 0.f;
      wv[jj] = pk2(x0, x1);
    }
    uint4 o; o.x = wv[0]; o.y = wv[1]; o.z = wv[2]; o.w = wv[3];
    ((uint4*)Apk)[idx] = o;
  } else if (blk < 70) {
    int idx = (blk - 50) * 256 + tid;          // 80 tiles * 64 lanes
    int lane = idx & 63, tile = idx >> 6;
    int kt = tile % 4, nt = tile / 4;
    int n  = nt * 16 + (lane & 15);
    int k0 = kt * 32 + (lane >> 4) * 8;
    uint32_t wv[4];
#pragma unroll
    for (int jj = 0; jj < 4; jj++) {
      int ka = k0 + 2 * jj, kb = ka + 1;
      float x0 = (n < S_DIM && ka < E_DIM) ? 128.f * Bm[n * E_DIM + ka] : 0.f;
      float x1 = (n < S_DIM && kb < E_DIM) ? 128.f * Bm[n * E_DIM + kb] : 0.f;
      wv[jj] = pk2(x0, x1);
    }
    uint4 o; o.x = wv[0]; o.y = wv[1]; o.z = wv[2]; o.w = wv[3];
    ((uint4*)Bfr)[idx] = o;
  } else {
    if (tid < NBATCH) out[tid] = 0.f;
  }
}

// ---- E precompute: E^T[t] fragments in main-loop register layout ----
// E^T = (128*Bmat) @ inp^T per t. Grid (T/TC, 2 batch-groups), 256 thr = 4 waves
// x 5 tiles. Lane packs its 4 f32 -> one uint2 at
// Efrag[(t*40 + bg*20 + nt)*64 + lane]  (512B fully-coalesced per wave-store).
// bar_lds() instead of __syncthreads(): keeps the t+2 inp prefetch in flight
// across the per-step barrier (same vmcnt-drain fix as the main kernel).
__global__ __launch_bounds__(256, 2)
void emis_pack(const uint32_t* __restrict__ Bfr, const float* __restrict__ inp,
               uint2* __restrict__ Efrag) {
  __shared__ __attribute__((aligned(16))) _Float16 inH[2][16 * 136];
  int tc = blockIdx.x, bg = blockIdx.y, bbase = bg * 16;
  int tid = threadIdx.x, lane = tid & 63, w = tid >> 6;
  int gl = lane & 15, quad = lane >> 4;

  half8 bfB[5][4];
#pragma unroll
  for (int q = 0; q < 5; q++)
#pragma unroll
    for (int kt = 0; kt < 4; kt++)
      bfB[q][kt] = h8_from_u4(((const uint4*)Bfr)[((w * 5 + q) * 4 + kt) * 64 + lane]);
#pragma unroll
  for (int q = 0; q < 5; q++)
#pragma unroll
    for (int kt = 0; kt < 4; kt++) asm volatile("" : "+v"(bfB[q][kt]));

  int t0 = tc * TC;
#pragma unroll
  for (int s = 0; s < 4; s++) {
    int flat = tid + s * 256;
    int r = flat >> 6, c2 = flat & 63;
    float2 v; v.x = 0.f; v.y = 0.f;
    if (c2 < 63) v = *(const float2*)(inp + ((size_t)(bbase + r) * T_LEN + t0) * E_DIM + 2 * c2);
    *(uint32_t*)&inH[0][r * 136 + 2 * c2] = pk2(v.x, v.y);
  }
  float2 g[4];   // prefetch t0+1
#pragma unroll
  for (int s = 0; s < 4; s++) {
    int flat = tid + s * 256;
    int r = flat >> 6, c2 = flat & 63;
    g[s].x = 0.f; g[s].y = 0.f;
    if (c2 < 63) g[s] = *(const float2*)(inp + ((size_t)(bbase + r) * T_LEN + (t0 + 1)) * E_DIM + 2 * c2);
  }
  bar_lds();

  for (int i = 0; i < TC; i++) {
    int cur = i & 1, t = t0 + i;
    floatx4 Ea[5];
#pragma unroll
    for (int q = 0; q < 5; q++) Ea[q] = (floatx4){0.f, 0.f, 0.f, 0.f};
#pragma unroll
    for (int kt = 0; kt < 4; kt++) {
      half8 af = h8_from_u4(*(const uint4*)&inH[cur][gl * 136 + kt * 32 + quad * 8]);
#pragma unroll
      for (int q = 0; q < 5; q++)
        Ea[q] = __builtin_amdgcn_mfma_f32_16x16x32_f16(bfB[q][kt], af, Ea[q], 0, 0, 0);
    }
    if (i < TC - 1) {
#pragma unroll
      for (int s = 0; s < 4; s++) {
        int flat = tid + s * 256;
        int r = flat >> 6, c2 = flat & 63;
        uint32_t pv = (c2 < 63) ? pk2(g[s].x, g[s].y) : 0u;
        *(uint32_t*)&inH[cur ^ 1][r * 136 + 2 * c2] = pv;
      }
      int tp = t0 + i + 2; if (tp > T_LEN - 1) tp = T_LEN - 1;
#pragma unroll
      for (int s = 0; s < 4; s++) {
        int flat = tid + s * 256;
        int r = flat >> 6, c2 = flat & 63;
        g[s].x = 0.f; g[s].y = 0.f;
        if (c2 < 63) g[s] = *(const float2*)(inp + ((size_t)(bbase + r) * T_LEN + tp) * E_DIM + 2 * c2);
      }
    }
#pragma unroll
    for (int q = 0; q < 5; q++) {
      uint2 o;
      o.x = pk2(Ea[q][0], Ea[q][1]);
      o.y = pk2(Ea[q][2], Ea[q][3]);
      Efrag[((size_t)t * 40 + bg * 20 + (w * 5 + q)) * 64 + lane] = o;
    }
    bar_lds();
  }
}

// ---- fused recursion, round-7: phase-skewed dual-stream + LDS-only barriers ----
// Round-4 lesson: three schedules all pinned at ~2600 cyc/barrier-interval ->
// the cost is __syncthreads' implicit s_waitcnt vmcnt(0), which drains the
// 5 in-flight Efrag loads (L3/HBM latency) at EVERY barrier. bar_lds() keeps
// them in flight; only DS ops (QL write->read, zslot atomics) are fenced,
// which is exactly the cross-wave dependency the barrier must order.
// Schedule per barrier interval (unchanged from round 4):
//   half 2k  : aY(k) writes QL_Y  ||  bX(k) reads QL_X + 50 MFMA + E-prefetch X
//   half 2k+1: aX(k+1) writes QL_X ||  bY(k) reads QL_Y + 50 MFMA + E-prefetch Y
// QROW=720B (180 dw == 20 mod 32): conflict-free b128 reads / b64 writes.
__global__ __launch_bounds__(256, 1)
void hmm_fused5(const uint32_t* __restrict__ Apk, const uint2* __restrict__ Efrag,
                const float* __restrict__ Ivec, float* __restrict__ out) {
  __shared__ __attribute__((aligned(16))) _Float16 QLX[16 * (QROW / 2)];
  __shared__ __attribute__((aligned(16))) _Float16 QLY[16 * (QROW / 2)];
  __shared__ float zX[16], zY[16];
  int bg = blockIdx.y, bbase = bg * 16;
  int cc0 = blockIdx.x * 2, cc1 = cc0 + 1;
  int tid = threadIdx.x, lane = tid & 63, w = tid >> 6;
  int gl = lane & 15, quad = lane >> 4;

  half8 bfA[5][10];
#pragma unroll
  for (int q = 0; q < 5; q++)
#pragma unroll
    for (int kt = 0; kt < 10; kt++)
      bfA[q][kt] = h8_from_u4(((const uint4*)Apk)[((w * 5 + q) * 10 + kt) * 64 + lane]);
#pragma unroll
  for (int q = 0; q < 5; q++)
#pragma unroll
    for (int kt = 0; kt < 10; kt++) asm volatile("" : "+v"(bfA[q][kt]));

  // P state-major: lane holds states (w*5+q)*16 + quad*4 + r for batch gl
  floatx4 PaX[5], PaY[5];
#pragma unroll
  for (int q = 0; q < 5; q++) {
    int sb = (w * 5 + q) * 16 + quad * 4;
#pragma unroll
    for (int r = 0; r < 4; r++) {
      int st = sb + r;
      PaX[q][r] = (st < S_DIM) ? ((cc0 == 0) ? Ivec[st] : 1.0f) : 0.f;
      PaY[q][r] = (st < S_DIM) ? 1.0f : 0.f;
    }
  }
  if (tid < 16) { zX[tid] = 0.f; zY[tid] = 0.f; }

  int tfX = cc0 * CHL - WARM + 1;   // -5 for cc0==0 (garbage warm, reset at IW)
  int tfY = cc1 * CHL - WARM + 1;

  // per-lane byte offset within an Efrag row
  ptrdiff_t laneoff = ((ptrdiff_t)bg * 1280 + (ptrdiff_t)(w * 5) * 64 + lane) * 8;
  const char* pX = (const char*)Efrag + (ptrdiff_t)(tfX - 1) * (ptrdiff_t)ROWB + laneoff;
  const char* pY = (const char*)Efrag + (ptrdiff_t)(tfY - 1) * (ptrdiff_t)ROWB + laneoff;

  uint2 EXa[5], EXb[5], EYa[5], EYb[5];
#pragma unroll
  for (int q = 0; q < 5; q++) EXa[q] = *(const uint2*)(pX + q * 512);
  pX += ROWB;
#pragma unroll
  for (int q = 0; q < 5; q++) EXb[q] = *(const uint2*)(pX + q * 512);
  pX += ROWB;
#pragma unroll
  for (int q = 0; q < 5; q++) EYa[q] = *(const uint2*)(pY + q * 512);
  pY += ROWB;
#pragma unroll
  for (int q = 0; q < 5; q++) EYb[q] = *(const uint2*)(pY + q * 512);
  pY += ROWB;

  const int wb = gl * QROW + w * 160 + quad * 8;   // write base (byte); +q*32
  const int rb = gl * QROW + quad * 16;            // read base (byte); +kt*64

  float llw0 = 0.f, llw1 = 0.f;

  // phase a: qv = P (.) E; optional z-checkpoint; optional QL write
  auto phA = [&](floatx4 (&Pa)[5], uint2 (&E)[5], _Float16* ql, float* zs,
                 bool zchk, bool wr) {
    float qv[5][4];
#pragma unroll
    for (int q = 0; q < 5; q++) {
      half4 ev = h4_from_u2(E[q]);
#pragma unroll
      for (int r = 0; r < 4; r++) qv[q][r] = Pa[q][r] * (float)ev[r];
    }
    if (zchk) {
      float z = 0.f;
#pragma unroll
      for (int q = 0; q < 5; q++) z += (qv[q][0] + qv[q][1]) + (qv[q][2] + qv[q][3]);
      z += __shfl_xor(z, 16); z += __shfl_xor(z, 32);
      if (lane < 16) atomicAdd(&zs[lane], z);
    }
    if (wr) {
#pragma unroll
      for (int q = 0; q < 5; q++) {
        uint2 o; o.x = pk2(qv[q][0], qv[q][1]); o.y = pk2(qv[q][2], qv[q][3]);
        *(uint2*)((char*)ql + wb + q * 32) = o;
      }
    }
  };
  // phase b: E-prefetch (running ptr) + P = A^T @ Q (10x ds_read_b128, 50 MFMA)
  auto phB = [&](floatx4 (&Pa)[5], const _Float16* ql, const char*& p, uint2 (&E)[5]) {
#pragma unroll
    for (int q = 0; q < 5; q++) E[q] = *(const uint2*)(p + q * 512);
    p += ROWB;
#pragma unroll
    for (int q = 0; q < 5; q++) Pa[q] = (floatx4){0.f, 0.f, 0.f, 0.f};
#pragma unroll
    for (int kt = 0; kt < 10; kt++) {
      half8 qf = h8_from_u4(*(const uint4*)((const char*)ql + rb + kt * 64));
#pragma unroll
      for (int q = 0; q < 5; q++)
        Pa[q] = __builtin_amdgcn_mfma_f32_16x16x32_f16(bfA[q][kt], qf, Pa[q], 0, 0, 0);
    }
  };
  auto phBnp = [&](floatx4 (&Pa)[5], const _Float16* ql) {   // tail: no prefetch
#pragma unroll
    for (int q = 0; q < 5; q++) Pa[q] = (floatx4){0.f, 0.f, 0.f, 0.f};
#pragma unroll
    for (int kt = 0; kt < 10; kt++) {
      half8 qf = h8_from_u4(*(const uint4*)((const char*)ql + rb + kt * 64));
#pragma unroll
      for (int q = 0; q < 5; q++)
        Pa[q] = __builtin_amdgcn_mfma_f32_16x16x32_f16(bfA[q][kt], qf, Pa[q], 0, 0, 0);
    }
  };

  // half 0: aX(0)
  phA(PaX, EXa, QLX, zX, false, true);
  bar_lds();

  for (int kk = 0; kk < NSTEP - 1; kk += 2) {
    // HALF_A(kk): bX(kk) [fills EXa] || aY(kk) [uses EYa]
    phB(PaX, QLX, pX, EXa);
    phA(PaY, EYa, QLY, zY, false, true);
    bar_lds();
    // HALF_B(kk): bY(kk) [fills EYa] || aX(kk+1) [uses EXb; z if kk+1==IW]
    phB(PaY, QLY, pY, EYa);
    phA(PaX, EXb, QLX, zX, (kk + 1 == IW), true);
    bar_lds();
    // HALF_A(kk+1): (llw0 read) bX(kk+1) [fills EXb] (+reset) || aY(kk+1) [EYb]
    if (kk + 1 == IW && tid < 16) { llw0 = cc0 ? logf(zX[tid]) : 0.f; zX[tid] = 0.f; }
    phB(PaX, QLX, pX, EXb);
    if (kk + 1 == IW && cc0 == 0) {
      // exact restart of chunk 0 at t=0 (its next phase-a uses E(0))
#pragma unroll
      for (int q = 0; q < 5; q++) {
        int sb = (w * 5 + q) * 16 + quad * 4;
#pragma unroll
        for (int r = 0; r < 4; r++) {
          int st = sb + r;
          PaX[q][r] = (st < S_DIM) ? Ivec[st] : 0.f;
        }
      }
    }
    phA(PaY, EYb, QLY, zY, (kk + 1 == IW), true);
    bar_lds();
    // HALF_B(kk+1): (llw1 read) bY(kk+1) [fills EYb] || aX(kk+2) [uses EXa]
    if (kk + 1 == IW && tid < 16) { llw1 = logf(zY[tid]); zY[tid] = 0.f; }
    phB(PaY, QLY, pY, EYb);
    phA(PaX, EXa, QLX, zX, false, true);
    bar_lds();
  }
  // tail k = NSTEP-1 = 20 (even):
  phBnp(PaX, QLX);                       // bX(20); prefetch target never consumed
  phA(PaY, EYa, QLY, zY, false, true);   // aY(20)
  bar_lds();
  phBnp(PaY, QLY);                       // bY(20)
  phA(PaX, EXb, QLX, zX, true, false);   // aX(21) = final-z X, no QL write
  bar_lds();
  phA(PaY, EYb, QLY, zY, true, false);   // aY(21) = final-z Y
  bar_lds();

  if (tid < 16) {
    float v = (logf(zX[tid]) - llw0) + (logf(zY[tid]) - llw1)
              - 2.0f * (float)CHL * LN128;   // CHL accounted x128 steps per stream
    atomicAdd(&out[bbase + tid], v);
  }
}

// ---- fallback (inp-direct, no Efrag workspace) ----
__global__ __launch_bounds__(640, 3)
void hmm_fused(const uint32_t* __restrict__ Apk,
               const uint32_t* __restrict__ Bfr,
               const float* __restrict__ inp,
               const float* __restrict__ Ivec,
               float* __restrict__ out) {
  __shared__ __attribute__((aligned(16))) _Float16 inH[2][16 * 136];
  __shared__ __attribute__((aligned(16))) _Float16 QLf[2][16 * 336];
  __shared__ float zslot[16];
  int c = blockIdx.x, bbase = blockIdx.y * 16;
  int tid = threadIdx.x, lane = tid & 63, w = tid >> 6;
  int gl = lane & 15, quad = lane >> 4;

  half8 bfA[2][10], bfB[2][4];
#pragma unroll
  for (int q = 0; q < 2; q++) {
#pragma unroll
    for (int kt = 0; kt < 10; kt++)
      bfA[q][kt] = h8_from_u4(((const uint4*)Apk)[((w * 2 + q) * 10 + kt) * 64 + lane]);
#pragma unroll
    for (int kt = 0; kt < 4; kt++)
      bfB[q][kt] = h8_from_u4(((const uint4*)Bfr)[((w * 2 + q) * 4 + kt) * 64 + lane]);
  }
#pragma unroll
  for (int q = 0; q < 2; q++) {
#pragma unroll
    for (int kt = 0; kt < 10; kt++) asm volatile("" : "+v"(bfA[q][kt]));
#pragma unroll
    for (int kt = 0; kt < 4; kt++)  asm volatile("" : "+v"(bfB[q][kt]));
  }

  float Pa[2][4];
#pragma unroll
  for (int q = 0; q < 2; q++) {
    int n = (w * 2 + q) * 16 + gl;
    float v = (n < S_DIM) ? (c == 0 ? Ivec[n] : 1.0f) : 0.f;
#pragma unroll
    for (int r = 0; r < 4; r++) Pa[q][r] = v;
  }
  if (tid < 16) zslot[tid] = 0.f;

  int t_first = (c == 0) ? 1 : (c * CHL - WARM + 1);
  int nstep   = (c == 0) ? (CHL - 1) : (CHL + WARM - 1);
  int iw      = (c == 0) ? -1 : (WARM - 1);
  int t_last  = t_first - 1 + nstep;

  {
    int t0 = t_first - 1;
#pragma unroll
    for (int s = 0; s < 2; s++) {
      int flat = tid + s * 640;
      if (flat < 1024) {
        int r = flat >> 6, c2 = flat & 63;
        float2 v; v.x = 0.f; v.y = 0.f;
        if (c2 < 63) v = *(const float2*)(inp + ((size_t)(bbase + r) * T_LEN + t0) * E_DIM + 2 * c2);
        *(uint32_t*)&inH[0][r * 136 + 2 * c2] = pk2(v.x, v.y);
      }
    }
  }
  float2 g[2];
#pragma unroll
  for (int s = 0; s < 2; s++) {
    int flat = tid + s * 640;
    g[s].x = 0.f; g[s].y = 0.f;
    if (flat < 1024) {
      int r = flat >> 6, c2 = flat & 63;
      if (c2 < 63) g[s] = *(const float2*)(inp + ((size_t)(bbase + r) * T_LEN + t_first) * E_DIM + 2 * c2);
    }
  }
  float llw = 0.f;
  __syncthreads();

  for (int i = 0; i <= nstep; i++) {
    int cur = i & 1, nxt = cur ^ 1;
    floatx4 Ea0 = (floatx4){0.f, 0.f, 0.f, 0.f};
    floatx4 Ea1 = (floatx4){0.f, 0.f, 0.f, 0.f};
#pragma unroll
    for (int kt = 0; kt < 4; kt++) {
      half8 af = h8_from_u4(*(const uint4*)&inH[cur][gl * 136 + kt * 32 + quad * 8]);
      Ea0 = __builtin_amdgcn_mfma_f32_16x16x32_f16(af, bfB[0][kt], Ea0, 0, 0, 0);
      Ea1 = __builtin_amdgcn_mfma_f32_16x16x32_f16(af, bfB[1][kt], Ea1, 0, 0, 0);
    }
    float qv[2][4];
#pragma unroll
    for (int r = 0; r < 4; r++) { qv[0][r] = Pa[0][r] * Ea0[r]; qv[1][r] = Pa[1][r] * Ea1[r]; }
    if (i == iw || i == nstep) {
      float s0 = qv[0][0] + qv[1][0], s1 = qv[0][1] + qv[1][1];
      float s2 = qv[0][2] + qv[1][2], s3 = qv[0][3] + qv[1][3];
#pragma unroll
      for (int off = 1; off <= 8; off <<= 1) {
        s0 += __shfl_xor(s0, off); s1 += __shfl_xor(s1, off);
        s2 += __shfl_xor(s2, off); s3 += __shfl_xor(s3, off);
      }
      if (gl == 0) {
        atomicAdd(&zslot[quad * 4 + 0], s0);
        atomicAdd(&zslot[quad * 4 + 1], s1);
        atomicAdd(&zslot[quad * 4 + 2], s2);
        atomicAdd(&zslot[quad * 4 + 3], s3);
      }
    }
#pragma unroll
    for (int q = 0; q < 2; q++) {
      int k = (w * 2 + q) * 16 + gl;
#pragma unroll
      for (int r = 0; r < 4; r++)
        QLf[cur][(quad * 4 + r) * 336 + k] = (_Float16)qv[q][r];
    }
    if (i < nstep) {
#pragma unroll
      for (int s = 0; s < 2; s++) {
        int flat = tid + s * 640;
        if (flat < 1024) {
          int r = flat >> 6, c2 = flat & 63;
          uint32_t pv = (c2 < 63) ? pk2(g[s].x, g[s].y) : 0u;
          *(uint32_t*)&inH[nxt][r * 136 + 2 * c2] = pv;
        }
      }
    }
    __syncthreads();
    if (i == iw && tid < 16) { llw = logf(zslot[tid]); zslot[tid] = 0.f; }
    if (i == nstep) {
      if (tid < 16) {
        float lle = logf(zslot[tid]);
        atomicAdd(&out[bbase + tid], lle - llw - (float)CHL * LN128);
      }
      break;
    }
    {
      int tp = t_first + i + 1; if (tp > t_last) tp = t_last;
#pragma unroll
      for (int s = 0; s < 2; s++) {
        int flat = tid + s * 640;
        g[s].x = 0.f; g[s].y = 0.f;
        if (flat < 1024) {
          int r = flat >> 6, c2 = flat & 63;
          if (c2 < 63) g[s] = *(const float2*)(inp + ((size_t)(bbase + r) * T_LEN + tp) * E_DIM + 2 * c2);
        }
      }
    }
    floatx4 acc0 = (floatx4){0.f, 0.f, 0.f, 0.f};
    floatx4 acc1 = (floatx4){0.f, 0.f, 0.f, 0.f};
#pragma unroll
    for (int kt = 0; kt < 10; kt++) {
      half8 afv = h8_from_u4(*(const uint4*)&QLf[cur][gl * 336 + kt * 32 + quad * 8]);
      acc0 = __builtin_amdgcn_mfma_f32_16x16x32_f16(afv, bfA[0][kt], acc0, 0, 0, 0);
      acc1 = __builtin_amdgcn_mfma_f32_16x16x32_f16(afv, bfA[1][kt], acc1, 0, 0, 0);
    }
#pragma unroll
    for (int r = 0; r < 4; r++) { Pa[0][r] = acc0[r]; Pa[1][r] = acc1[r]; }
  }
}

extern "C" void kernel_launch(void* const* d_in, const int* in_sizes, int n_in,
                              void* d_out, int out_size, void* d_ws, size_t ws_size,
                              hipStream_t stream) {
  const float* inp = (const float*)d_in[0];   // [32,4096,126]
  const float* A   = (const float*)d_in[1];   // [308,308]
  const float* Bm  = (const float*)d_in[2];   // [308,126]
  const float* Iv  = (const float*)d_in[3];   // [308]
  float* out = (float*)d_out;                 // [32]

  uint8_t* ws = (uint8_t*)d_ws;
  uint32_t* Apk = (uint32_t*)(ws);                 // 200 KiB
  uint32_t* Bfr = (uint32_t*)(ws + (256u << 10));  // 80 KiB
  const size_t EOFF   = (size_t)384 << 10;
  const size_t EBYTES = (size_t)T_LEN * ROWB;      // 80 MiB (rows t = 0..4095)

  hipLaunchKernelGGL(init_pack, dim3(71), dim3(256), 0, stream, A, Bm, Apk, Bfr, out);
  if (ws_size >= EOFF + EBYTES) {
    uint2* Efrag = (uint2*)(ws + EOFF);
    hipLaunchKernelGGL(emis_pack, dim3(T_LEN / TC, 2), dim3(256), 0, stream, Bfr, inp, Efrag);
    hipLaunchKernelGGL(hmm_fused5, dim3(NCH / 2, NBATCH / 16), dim3(256), 0, stream,
                       Apk, Efrag, Iv, out);
  } else {
    hipLaunchKernelGGL(hmm_fused, dim3(NCH, NBATCH / 16), dim3(640), 0, stream,
                       Apk, Bfr, inp, Iv, out);
  }
}

// Round 6
// 157.304 us; speedup vs baseline: 1.0234x; 1.0234x over previous
//
#include <hip/hip_runtime.h>
#include <cstdint>
#include <cstddef>

#define T_LEN 4096
#define S_DIM 308
#define E_DIM 126
#define NBATCH 32
#define CHL 16                     // chunk length: 256 chunks, 2 per block (lockstep)
#define NCH (T_LEN / CHL)          // 256
#define WARM 6                     // contraction ~0.066/step -> ~1e-6 relative after warm-up
#define NSTEP (CHL + WARM - 1)     // 21, uniform for ALL chunks (c==0 uses reset-at-IW)
#define IW (WARM - 1)              // checkpoint substep (z at t = c*CHL-1)
#define QROW 720                   // QL row stride BYTES = 180 dw == 20 (mod 32):
                                   //   b128 reads 8/bank, b64 writes 4/bank = conflict-free
#define TC 16                      // emis_pack timesteps per block
#define LN128 4.852030263919617f   // ln(128): per-step prescale to telescope out

typedef _Float16 half8 __attribute__((ext_vector_type(8)));
typedef _Float16 half4 __attribute__((ext_vector_type(4)));
typedef float floatx4 __attribute__((ext_vector_type(4)));

union HU8 { uint4 u; half8 h; };
union HU4 { uint2 u; half4 h; };
union HU1 { uint16_t u; _Float16 h; };

__device__ __forceinline__ half8 h8_from_u4(uint4 v) { HU8 t; t.u = v; return t.h; }
__device__ __forceinline__ half4 h4_from_u2(uint2 v) { HU4 t; t.u = v; return t.h; }
__device__ __forceinline__ half8 h8_zero() { uint4 z; z.x = z.y = z.z = z.w = 0u; return h8_from_u4(z); }
__device__ __forceinline__ uint32_t pk2(float x, float y) {
  HU1 a, b; a.h = (_Float16)x; b.h = (_Float16)y;
  return (uint32_t)a.u | ((uint32_t)b.u << 16);
}

// ---- merged init: blocks 0..49 pack A-frags, 50..69 pack B-frags, 70 zeroes out ----
// A-frag: tile = nt*10 + kt; lane l holds A[k=kt*32+(l>>4)*8+j][n=nt*16+(l&15)], j=0..7.
// Serves as MFMA A-operand for P^T = A^T @ Q^T (m = out-state, k = in-state).
// B-frag: tile = nt*4 + kt over E padded to 128, value = 128*B[n][k]; MFMA A-operand
// for E^T = (128*Bmat) @ inp^T in emis_pack. x128 telescopes into the loglik.
__global__ __launch_bounds__(256) void init_pack(const float* __restrict__ A,
                                                 const float* __restrict__ Bm,
                                                 uint32_t* __restrict__ Apk,
                                                 uint32_t* __restrict__ Bfr,
                                                 float* __restrict__ out) {
  int blk = blockIdx.x, tid = threadIdx.x;
  if (blk < 50) {
    int idx = blk * 256 + tid;                 // 200 tiles * 64 lanes
    int lane = idx & 63, tile = idx >> 6;
    int kt = tile % 10, nt = tile / 10;
    int n  = nt * 16 + (lane & 15);
    int k0 = kt * 32 + (lane >> 4) * 8;
    uint32_t wv[4];
#pragma unroll
    for (int jj = 0; jj < 4; jj++) {
      int ka = k0 + 2 * jj, kb = ka + 1;
      float x0 = (n < S_DIM && ka < S_DIM) ? A[ka * S_DIM + n] : 0.f;
      float x1 = (n < S_DIM && kb < S_DIM) ? A[kb * S_DIM + n] : 0.f;
      wv[jj] = pk2(x0, x1);
    }
    uint4 o; o.x = wv[0]; o.y = wv[1]; o.z = wv[2]; o.w = wv[3];
    ((uint4*)Apk)[idx] = o;
  } else if (blk < 70) {
    int idx = (blk - 50) * 256 + tid;          // 80 tiles * 64 lanes
    int lane = idx & 63, tile = idx >> 6;
    int kt = tile % 4, nt = tile / 4;
    int n  = nt * 16 + (lane & 15);
    int k0 = kt * 32 + (lane >> 4) * 8;
    uint32_t wv[4];
#pragma unroll
    for (int jj = 0; jj < 4; jj++) {
      int ka = k0 + 2 * jj, kb = ka + 1;
      float x0 = (n < S_DIM && ka < E_DIM) ? 128.f * Bm[n * E_DIM + ka] : 0.f;
      float x1 = (n < S_DIM && kb < E_DIM) ? 128.f * Bm[n * E_DIM + kb] : 0.f;
      wv[jj] = pk2(x0, x1);
    }
    uint4 o; o.x = wv[0]; o.y = wv[1]; o.z = wv[2]; o.w = wv[3];
    ((uint4*)Bfr)[idx] = o;
  } else {
    if (tid < NBATCH) out[tid] = 0.f;
  }
}

// ---- E precompute: E^T[t] fragments in main-loop register layout ----
// E^T = (128*Bmat) @ inp^T per t. Grid (T/TC, 2 batch-groups), 256 thr = 4 waves
// x 5 tiles. Lane packs its 4 f32 -> one uint2 at
// Efrag[(t*40 + bg*20 + nt)*64 + lane]  (512B fully-coalesced per wave-store).
// __syncthreads throughout (round-5 lesson: inline-asm barriers disrupt the
// compiler's load scheduling and cost more than the vmcnt drain saves).
__global__ __launch_bounds__(256, 2)
void emis_pack(const uint32_t* __restrict__ Bfr, const float* __restrict__ inp,
               uint2* __restrict__ Efrag) {
  __shared__ __attribute__((aligned(16))) _Float16 inH[2][16 * 136];
  int tc = blockIdx.x, bg = blockIdx.y, bbase = bg * 16;
  int tid = threadIdx.x, lane = tid & 63, w = tid >> 6;
  int gl = lane & 15, quad = lane >> 4;

  half8 bfB[5][4];
#pragma unroll
  for (int q = 0; q < 5; q++)
#pragma unroll
    for (int kt = 0; kt < 4; kt++)
      bfB[q][kt] = h8_from_u4(((const uint4*)Bfr)[((w * 5 + q) * 4 + kt) * 64 + lane]);
#pragma unroll
  for (int q = 0; q < 5; q++)
#pragma unroll
    for (int kt = 0; kt < 4; kt++) asm volatile("" : "+v"(bfB[q][kt]));

  int t0 = tc * TC;
#pragma unroll
  for (int s = 0; s < 4; s++) {
    int flat = tid + s * 256;
    int r = flat >> 6, c2 = flat & 63;
    float2 v; v.x = 0.f; v.y = 0.f;
    if (c2 < 63) v = *(const float2*)(inp + ((size_t)(bbase + r) * T_LEN + t0) * E_DIM + 2 * c2);
    *(uint32_t*)&inH[0][r * 136 + 2 * c2] = pk2(v.x, v.y);
  }
  float2 g[4];   // prefetch t0+1
#pragma unroll
  for (int s = 0; s < 4; s++) {
    int flat = tid + s * 256;
    int r = flat >> 6, c2 = flat & 63;
    g[s].x = 0.f; g[s].y = 0.f;
    if (c2 < 63) g[s] = *(const float2*)(inp + ((size_t)(bbase + r) * T_LEN + (t0 + 1)) * E_DIM + 2 * c2);
  }
  __syncthreads();

  for (int i = 0; i < TC; i++) {
    int cur = i & 1, t = t0 + i;
    floatx4 Ea[5];
#pragma unroll
    for (int q = 0; q < 5; q++) Ea[q] = (floatx4){0.f, 0.f, 0.f, 0.f};
#pragma unroll
    for (int kt = 0; kt < 4; kt++) {
      half8 af = h8_from_u4(*(const uint4*)&inH[cur][gl * 136 + kt * 32 + quad * 8]);
#pragma unroll
      for (int q = 0; q < 5; q++)
        Ea[q] = __builtin_amdgcn_mfma_f32_16x16x32_f16(bfB[q][kt], af, Ea[q], 0, 0, 0);
    }
    if (i < TC - 1) {
#pragma unroll
      for (int s = 0; s < 4; s++) {
        int flat = tid + s * 256;
        int r = flat >> 6, c2 = flat & 63;
        uint32_t pv = (c2 < 63) ? pk2(g[s].x, g[s].y) : 0u;
        *(uint32_t*)&inH[cur ^ 1][r * 136 + 2 * c2] = pv;
      }
      int tp = t0 + i + 2; if (tp > T_LEN - 1) tp = T_LEN - 1;
#pragma unroll
      for (int s = 0; s < 4; s++) {
        int flat = tid + s * 256;
        int r = flat >> 6, c2 = flat & 63;
        g[s].x = 0.f; g[s].y = 0.f;
        if (c2 < 63) g[s] = *(const float2*)(inp + ((size_t)(bbase + r) * T_LEN + tp) * E_DIM + 2 * c2);
      }
    }
#pragma unroll
    for (int q = 0; q < 5; q++) {
      uint2 o;
      o.x = pk2(Ea[q][0], Ea[q][1]);
      o.y = pk2(Ea[q][2], Ea[q][3]);
      Efrag[((size_t)t * 40 + bg * 20 + (w * 5 + q)) * 64 + lane] = o;
    }
    __syncthreads();
  }
}

// ---- fused recursion, round-8: 8 waves = 2 waves/SIMD (TLP latency hiding) ----
// Round-5 diagnosis: all prior schedules ran 1 wave/SIMD (A-in-regs is ~390
// regs/wave at 4 waves) -> every ds_read/MFMA-chain/barrier latency fully
// exposed; three different schedules converged on the same ~2600 cyc constant.
// Fix: 512 thr = 8 waves; tile split 3/3/3/3/2/2/2/2 so SIMD s hosts waves
// {s, s+4} = 5 tiles -> per-SIMD balanced AND per-wave regs ~212 < 256, so
// __launch_bounds__(512,2) keeps BOTH waves resident: one wave's issue fills
// the other's stalls. Lockstep dual-stream (one barrier per pair-step), QL
// double-buffered per stream, QROW=720B conflict-free layout. E prefetch
// (depth-2) issued at the TOP of phase b so its latency hides under the
// MFMA/LDS work before the next barrier's implicit vmcnt drain.
__global__ __launch_bounds__(512, 2)
void hmm_fused6(const uint32_t* __restrict__ Apk, const uint2* __restrict__ Efrag,
                const float* __restrict__ Ivec, float* __restrict__ out) {
  __shared__ __attribute__((aligned(16))) _Float16 QL[2][2][16 * 360]; // [stream][buf]
  __shared__ float zsl[2][16];
  int bg = blockIdx.y, bbase = bg * 16;
  int cc0 = blockIdx.x * 2, cc1 = cc0 + 1;
  int tid = threadIdx.x, lane = tid & 63, w = tid >> 6;
  int gl = lane & 15, quad = lane >> 4;
  int base = (w < 4) ? 3 * w : 12 + 2 * (w - 4);   // first n-tile owned by this wave
  int cnt  = (w < 4) ? 3 : 2;                      // tiles owned (SIMD-pair = 5)

  half8 bfA[3][10];
#pragma unroll
  for (int q = 0; q < 3; q++)
#pragma unroll
    for (int kt = 0; kt < 10; kt++)
      bfA[q][kt] = (q < cnt)
        ? h8_from_u4(((const uint4*)Apk)[((base + q) * 10 + kt) * 64 + lane])
        : h8_zero();
#pragma unroll
  for (int q = 0; q < 3; q++)
#pragma unroll
    for (int kt = 0; kt < 10; kt++) asm volatile("" : "+v"(bfA[q][kt]));

  // P state-major: lane holds states (base+q)*16 + quad*4 + r for batch gl
  floatx4 Pa[2][3];
#pragma unroll
  for (int q = 0; q < 3; q++)
#pragma unroll
    for (int r = 0; r < 4; r++) {
      int st = (base + q) * 16 + quad * 4 + r;
      bool ok = (q < cnt) && (st < S_DIM);
      Pa[0][q][r] = ok ? ((cc0 == 0) ? Ivec[st] : 1.0f) : 0.f;
      Pa[1][q][r] = ok ? 1.0f : 0.f;
    }
  if (tid < 32) zsl[tid >> 4][tid & 15] = 0.f;

  int tfX = cc0 * CHL - WARM + 1;   // -5 for cc0==0 (garbage warm, reset at IW)
  int tfY = cc1 * CHL - WARM + 1;
  int tlX = tfX + NSTEP - 1, tlY = tfY + NSTEP - 1;

  size_t ebase = (size_t)bg * 1280 + (size_t)base * 64 + lane;
  uint2 EA[2][3], EB[2][3];
  EA[0][2] = EA[1][2] = EB[0][2] = EB[1][2] = (uint2){0u, 0u};
  {
    int ta0 = tfX - 1; if (ta0 < 0) ta0 = 0;
    int tb0 = tfX;     if (tb0 < 0) tb0 = 0;
    int ta1 = tfY - 1; if (ta1 < 0) ta1 = 0;
    int tb1 = tfY;
#pragma unroll
    for (int q = 0; q < 3; q++)
      if (q < cnt) {
        EA[0][q] = Efrag[(size_t)ta0 * 2560 + ebase + (size_t)q * 64];
        EB[0][q] = Efrag[(size_t)tb0 * 2560 + ebase + (size_t)q * 64];
        EA[1][q] = Efrag[(size_t)ta1 * 2560 + ebase + (size_t)q * 64];
        EB[1][q] = Efrag[(size_t)tb1 * 2560 + ebase + (size_t)q * 64];
      }
  }

  float llw0 = 0.f, llw1 = 0.f;

  auto step = [&](uint2 (&E)[2][3], int ii) {
    int cur = ii & 1;
    // ---- phase a: Q = P (.) E, both streams (registers only)
    float qv[2][3][4];
#pragma unroll
    for (int s = 0; s < 2; s++)
#pragma unroll
      for (int q = 0; q < 3; q++)
        if (q < cnt) {
          half4 ev = h4_from_u2(E[s][q]);
#pragma unroll
          for (int r = 0; r < 4; r++) qv[s][q][r] = Pa[s][q][r] * (float)ev[r];
        }
    // checkpoints: z[b] = sum_s Q[s][b]
    if (ii == IW || ii == NSTEP) {
#pragma unroll
      for (int s = 0; s < 2; s++) {
        float z = 0.f;
#pragma unroll
        for (int q = 0; q < 3; q++)
          if (q < cnt) z += (qv[s][q][0] + qv[s][q][1]) + (qv[s][q][2] + qv[s][q][3]);
        z += __shfl_xor(z, 16); z += __shfl_xor(z, 32);
        if (lane < 16) atomicAdd(&zsl[s][lane], z);
      }
    }
    // write Q -> QL[s][cur]: 4 consecutive k-states per lane -> one b64 per tile
#pragma unroll
    for (int s = 0; s < 2; s++)
#pragma unroll
      for (int q = 0; q < 3; q++)
        if (q < cnt) {
          uint2 o;
          o.x = pk2(qv[s][q][0], qv[s][q][1]);
          o.y = pk2(qv[s][q][2], qv[s][q][3]);
          *(uint2*)((char*)&QL[s][cur][0] + gl * QROW + (base + q) * 32 + quad * 8) = o;
        }
    __syncthreads();   // the ONLY barrier per pair-step
    if (ii == IW) {
      if (tid < 16) {
        llw0 = cc0 ? logf(zsl[0][tid]) : 0.f;    // cc0==0: garbage warm, llw stays 0
        llw1 = logf(zsl[1][tid]);
        zsl[0][tid] = 0.f; zsl[1][tid] = 0.f;
      }
    }
    if (ii == NSTEP) {
      if (tid < 16) {
        float v = (logf(zsl[0][tid]) - llw0) + (logf(zsl[1][tid]) - llw1)
                  - 2.0f * (float)CHL * LN128;   // CHL accounted x128 steps per stream
        atomicAdd(&out[bbase + tid], v);
      }
      return;
    }
    // ---- phase b: E prefetch first (latency hides under MFMA/LDS below)
    {
      int tpX = tfX + ii + 1; if (tpX < 0) tpX = 0; if (tpX > tlX) tpX = tlX;
      int tpY = tfY + ii + 1; if (tpY < 0) tpY = 0; if (tpY > tlY) tpY = tlY;
#pragma unroll
      for (int q = 0; q < 3; q++)
        if (q < cnt) {
          E[0][q] = Efrag[(size_t)tpX * 2560 + ebase + (size_t)q * 64];
          E[1][q] = Efrag[(size_t)tpY * 2560 + ebase + (size_t)q * 64];
        }
    }
    // P^T = A^T @ Q^T, both streams: full-k ds_read, up-to-6 MFMA per kt
    // (dual-stream interleave spaces same-accumulator MFMAs ~6 issues apart)
    floatx4 aX[3], aY[3];
#pragma unroll
    for (int q = 0; q < 3; q++) { aX[q] = (floatx4){0.f,0.f,0.f,0.f}; aY[q] = aX[q]; }
#pragma unroll
    for (int kt = 0; kt < 10; kt++) {
      half8 q0 = h8_from_u4(*(const uint4*)((const char*)&QL[0][cur][0] + gl * QROW + quad * 16 + kt * 64));
      half8 q1 = h8_from_u4(*(const uint4*)((const char*)&QL[1][cur][0] + gl * QROW + quad * 16 + kt * 64));
#pragma unroll
      for (int q = 0; q < 3; q++)
        if (q < cnt) {
          aX[q] = __builtin_amdgcn_mfma_f32_16x16x32_f16(bfA[q][kt], q0, aX[q], 0, 0, 0);
          aY[q] = __builtin_amdgcn_mfma_f32_16x16x32_f16(bfA[q][kt], q1, aY[q], 0, 0, 0);
        }
    }
#pragma unroll
    for (int q = 0; q < 3; q++) { Pa[0][q] = aX[q]; Pa[1][q] = aY[q]; }
    if (ii == IW && cc0 == 0) {
      // exact restart of chunk 0 at t=0 (its next phase-a uses E(0))
#pragma unroll
      for (int q = 0; q < 3; q++)
#pragma unroll
        for (int r = 0; r < 4; r++) {
          int st = (base + q) * 16 + quad * 4 + r;
          Pa[0][q][r] = ((q < cnt) && st < S_DIM) ? Ivec[st] : 0.f;
        }
    }
  };

  // NSTEP odd -> even number of steps; EA/EB statically selected
  for (int i = 0; i <= NSTEP; i += 2) {
    step(EA, i);
    step(EB, i + 1);
  }
}

// ---- fallback (inp-direct, no Efrag workspace) ----
__global__ __launch_bounds__(640, 3)
void hmm_fused(const uint32_t* __restrict__ Apk,
               const uint32_t* __restrict__ Bfr,
               const float* __restrict__ inp,
               const float* __restrict__ Ivec,
               float* __restrict__ out) {
  __shared__ __attribute__((aligned(16))) _Float16 inH[2][16 * 136];
  __shared__ __attribute__((aligned(16))) _Float16 QLf[2][16 * 336];
  __shared__ float zslot[16];
  int c = blockIdx.x, bbase = blockIdx.y * 16;
  int tid = threadIdx.x, lane = tid & 63, w = tid >> 6;
  int gl = lane & 15, quad = lane >> 4;

  half8 bfA[2][10], bfB[2][4];
#pragma unroll
  for (int q = 0; q < 2; q++) {
#pragma unroll
    for (int kt = 0; kt < 10; kt++)
      bfA[q][kt] = h8_from_u4(((const uint4*)Apk)[((w * 2 + q) * 10 + kt) * 64 + lane]);
#pragma unroll
    for (int kt = 0; kt < 4; kt++)
      bfB[q][kt] = h8_from_u4(((const uint4*)Bfr)[((w * 2 + q) * 4 + kt) * 64 + lane]);
  }
#pragma unroll
  for (int q = 0; q < 2; q++) {
#pragma unroll
    for (int kt = 0; kt < 10; kt++) asm volatile("" : "+v"(bfA[q][kt]));
#pragma unroll
    for (int kt = 0; kt < 4; kt++)  asm volatile("" : "+v"(bfB[q][kt]));
  }

  float Pa[2][4];
#pragma unroll
  for (int q = 0; q < 2; q++) {
    int n = (w * 2 + q) * 16 + gl;
    float v = (n < S_DIM) ? (c == 0 ? Ivec[n] : 1.0f) : 0.f;
#pragma unroll
    for (int r = 0; r < 4; r++) Pa[q][r] = v;
  }
  if (tid < 16) zslot[tid] = 0.f;

  int t_first = (c == 0) ? 1 : (c * CHL - WARM + 1);
  int nstep   = (c == 0) ? (CHL - 1) : (CHL + WARM - 1);
  int iw      = (c == 0) ? -1 : (WARM - 1);
  int t_last  = t_first - 1 + nstep;

  {
    int t0 = t_first - 1;
#pragma unroll
    for (int s = 0; s < 2; s++) {
      int flat = tid + s * 640;
      if (flat < 1024) {
        int r = flat >> 6, c2 = flat & 63;
        float2 v; v.x = 0.f; v.y = 0.f;
        if (c2 < 63) v = *(const float2*)(inp + ((size_t)(bbase + r) * T_LEN + t0) * E_DIM + 2 * c2);
        *(uint32_t*)&inH[0][r * 136 + 2 * c2] = pk2(v.x, v.y);
      }
    }
  }
  float2 g[2];
#pragma unroll
  for (int s = 0; s < 2; s++) {
    int flat = tid + s * 640;
    g[s].x = 0.f; g[s].y = 0.f;
    if (flat < 1024) {
      int r = flat >> 6, c2 = flat & 63;
      if (c2 < 63) g[s] = *(const float2*)(inp + ((size_t)(bbase + r) * T_LEN + t_first) * E_DIM + 2 * c2);
    }
  }
  float llw = 0.f;
  __syncthreads();

  for (int i = 0; i <= nstep; i++) {
    int cur = i & 1, nxt = cur ^ 1;
    floatx4 Ea0 = (floatx4){0.f, 0.f, 0.f, 0.f};
    floatx4 Ea1 = (floatx4){0.f, 0.f, 0.f, 0.f};
#pragma unroll
    for (int kt = 0; kt < 4; kt++) {
      half8 af = h8_from_u4(*(const uint4*)&inH[cur][gl * 136 + kt * 32 + quad * 8]);
      Ea0 = __builtin_amdgcn_mfma_f32_16x16x32_f16(af, bfB[0][kt], Ea0, 0, 0, 0);
      Ea1 = __builtin_amdgcn_mfma_f32_16x16x32_f16(af, bfB[1][kt], Ea1, 0, 0, 0);
    }
    float qv[2][4];
#pragma unroll
    for (int r = 0; r < 4; r++) { qv[0][r] = Pa[0][r] * Ea0[r]; qv[1][r] = Pa[1][r] * Ea1[r]; }
    if (i == iw || i == nstep) {
      float s0 = qv[0][0] + qv[1][0], s1 = qv[0][1] + qv[1][1];
      float s2 = qv[0][2] + qv[1][2], s3 = qv[0][3] + qv[1][3];
#pragma unroll
      for (int off = 1; off <= 8; off <<= 1) {
        s0 += __shfl_xor(s0, off); s1 += __shfl_xor(s1, off);
        s2 += __shfl_xor(s2, off); s3 += __shfl_xor(s3, off);
      }
      if (gl == 0) {
        atomicAdd(&zslot[quad * 4 + 0], s0);
        atomicAdd(&zslot[quad * 4 + 1], s1);
        atomicAdd(&zslot[quad * 4 + 2], s2);
        atomicAdd(&zslot[quad * 4 + 3], s3);
      }
    }
#pragma unroll
    for (int q = 0; q < 2; q++) {
      int k = (w * 2 + q) * 16 + gl;
#pragma unroll
      for (int r = 0; r < 4; r++)
        QLf[cur][(quad * 4 + r) * 336 + k] = (_Float16)qv[q][r];
    }
    if (i < nstep) {
#pragma unroll
      for (int s = 0; s < 2; s++) {
        int flat = tid + s * 640;
        if (flat < 1024) {
          int r = flat >> 6, c2 = flat & 63;
          uint32_t pv = (c2 < 63) ? pk2(g[s].x, g[s].y) : 0u;
          *(uint32_t*)&inH[nxt][r * 136 + 2 * c2] = pv;
        }
      }
    }
    __syncthreads();
    if (i == iw && tid < 16) { llw = logf(zslot[tid]); zslot[tid] = 0.f; }
    if (i == nstep) {
      if (tid < 16) {
        float lle = logf(zslot[tid]);
        atomicAdd(&out[bbase + tid], lle - llw - (float)CHL * LN128);
      }
      break;
    }
    {
      int tp = t_first + i + 1; if (tp > t_last) tp = t_last;
#pragma unroll
      for (int s = 0; s < 2; s++) {
        int flat = tid + s * 640;
        g[s].x = 0.f; g[s].y = 0.f;
        if (flat < 1024) {
          int r = flat >> 6, c2 = flat & 63;
          if (c2 < 63) g[s] = *(const float2*)(inp + ((size_t)(bbase + r) * T_LEN + tp) * E_DIM + 2 * c2);
        }
      }
    }
    floatx4 acc0 = (floatx4){0.f, 0.f, 0.f, 0.f};
    floatx4 acc1 = (floatx4){0.f, 0.f, 0.f, 0.f};
#pragma unroll
    for (int kt = 0; kt < 10; kt++) {
      half8 afv = h8_from_u4(*(const uint4*)&QLf[cur][gl * 336 + kt * 32 + quad * 8]);
      acc0 = __builtin_amdgcn_mfma_f32_16x16x32_f16(afv, bfA[0][kt], acc0, 0, 0, 0);
      acc1 = __builtin_amdgcn_mfma_f32_16x16x32_f16(afv, bfA[1][kt], acc1, 0, 0, 0);
    }
#pragma unroll
    for (int r = 0; r < 4; r++) { Pa[0][r] = acc0[r]; Pa[1][r] = acc1[r]; }
  }
}

extern "C" void kernel_launch(void* const* d_in, const int* in_sizes, int n_in,
                              void* d_out, int out_size, void* d_ws, size_t ws_size,
                              hipStream_t stream) {
  const float* inp = (const float*)d_in[0];   // [32,4096,126]
  const float* A   = (const float*)d_in[1];   // [308,308]
  const float* Bm  = (const float*)d_in[2];   // [308,126]
  const float* Iv  = (const float*)d_in[3];   // [308]
  float* out = (float*)d_out;                 // [32]

  uint8_t* ws = (uint8_t*)d_ws;
  uint32_t* Apk = (uint32_t*)(ws);                 // 200 KiB
  uint32_t* Bfr = (uint32_t*)(ws + (256u << 10));  // 80 KiB
  const size_t EOFF   = (size_t)384 << 10;
  const size_t EBYTES = (size_t)T_LEN * 40 * 64 * sizeof(uint2);  // 80 MiB

  hipLaunchKernelGGL(init_pack, dim3(71), dim3(256), 0, stream, A, Bm, Apk, Bfr, out);
  if (ws_size >= EOFF + EBYTES) {
    uint2* Efrag = (uint2*)(ws + EOFF);
    hipLaunchKernelGGL(emis_pack, dim3(T_LEN / TC, 2), dim3(256), 0, stream, Bfr, inp, Efrag);
    hipLaunchKernelGGL(hmm_fused6, dim3(NCH / 2, NBATCH / 16), dim3(512), 0, stream,
                       Apk, Efrag, Iv, out);
  } else {
    hipLaunchKernelGGL(hmm_fused, dim3(NCH, NBATCH / 16), dim3(640), 0, stream,
                       Apk, Bfr, inp, Iv, out);
  }
}

// Round 7
// 156.736 us; speedup vs baseline: 1.0271x; 1.0036x over previous
//
#include <hip/hip_runtime.h>
#include <cstdint>
#include <cstddef>

#define T_LEN 4096
#define S_DIM 308
#define E_DIM 126
#define NBATCH 32
#define CHL 16                     // chunk length: 256 chunks, 2 per block (lockstep)
#define NCH (T_LEN / CHL)          // 256
#define WARM 6                     // contraction ~0.066/step -> ~1e-6 relative after warm-up
#define NSTEP (CHL + WARM - 1)     // 21, uniform for ALL chunks (c==0 uses reset-at-IW)
#define IW (WARM - 1)              // checkpoint substep (z at t = c*CHL-1)
#define TC 16                      // emis_pack timesteps per block
#define LN128 4.852030263919617f   // ln(128): per-step prescale to telescope out

typedef _Float16 half8 __attribute__((ext_vector_type(8)));
typedef _Float16 half4 __attribute__((ext_vector_type(4)));
typedef float floatx4 __attribute__((ext_vector_type(4)));

union HU8 { uint4 u; half8 h; };
union HU4 { uint2 u; half4 h; };
union HU1 { uint16_t u; _Float16 h; };

__device__ __forceinline__ half8 h8_from_u4(uint4 v) { HU8 t; t.u = v; return t.h; }
__device__ __forceinline__ half4 h4_from_u2(uint2 v) { HU4 t; t.u = v; return t.h; }
__device__ __forceinline__ half8 h8_zero() { uint4 z; z.x = z.y = z.z = z.w = 0u; return h8_from_u4(z); }
__device__ __forceinline__ uint32_t pk2(float x, float y) {
  HU1 a, b; a.h = (_Float16)x; b.h = (_Float16)y;
  return (uint32_t)a.u | ((uint32_t)b.u << 16);
}

// ---- merged init: blocks 0..49 pack A-frags, 50..69 pack B-frags, 70 zeroes out ----
// A-frag: tile = nt*10 + kt; lane l holds A[k=kt*32+(l>>4)*8+j][n=nt*16+(l&15)], j=0..7.
// Serves as MFMA A-operand for P^T = A^T @ Q^T (m = out-state, k = in-state).
// B-frag: tile = nt*4 + kt over E padded to 128, value = 128*B[n][k]; MFMA A-operand
// for E^T = (128*Bmat) @ inp^T in emis_pack. x128 telescopes into the loglik.
__global__ __launch_bounds__(256) void init_pack(const float* __restrict__ A,
                                                 const float* __restrict__ Bm,
                                                 uint32_t* __restrict__ Apk,
                                                 uint32_t* __restrict__ Bfr,
                                                 float* __restrict__ out) {
  int blk = blockIdx.x, tid = threadIdx.x;
  if (blk < 50) {
    int idx = blk * 256 + tid;                 // 200 tiles * 64 lanes
    int lane = idx & 63, tile = idx >> 6;
    int kt = tile % 10, nt = tile / 10;
    int n  = nt * 16 + (lane & 15);
    int k0 = kt * 32 + (lane >> 4) * 8;
    uint32_t wv[4];
#pragma unroll
    for (int jj = 0; jj < 4; jj++) {
      int ka = k0 + 2 * jj, kb = ka + 1;
      float x0 = (n < S_DIM && ka < S_DIM) ? A[ka * S_DIM + n] : 0.f;
      float x1 = (n < S_DIM && kb < S_DIM) ? A[kb * S_DIM + n] : 0.f;
      wv[jj] = pk2(x0, x1);
    }
    uint4 o; o.x = wv[0]; o.y = wv[1]; o.z = wv[2]; o.w = wv[3];
    ((uint4*)Apk)[idx] = o;
  } else if (blk < 70) {
    int idx = (blk - 50) * 256 + tid;          // 80 tiles * 64 lanes
    int lane = idx & 63, tile = idx >> 6;
    int kt = tile % 4, nt = tile / 4;
    int n  = nt * 16 + (lane & 15);
    int k0 = kt * 32 + (lane >> 4) * 8;
    uint32_t wv[4];
#pragma unroll
    for (int jj = 0; jj < 4; jj++) {
      int ka = k0 + 2 * jj, kb = ka + 1;
      float x0 = (n < S_DIM && ka < E_DIM) ? 128.f * Bm[n * E_DIM + ka] : 0.f;
      float x1 = (n < S_DIM && kb < E_DIM) ? 128.f * Bm[n * E_DIM + kb] : 0.f;
      wv[jj] = pk2(x0, x1);
    }
    uint4 o; o.x = wv[0]; o.y = wv[1]; o.z = wv[2]; o.w = wv[3];
    ((uint4*)Bfr)[idx] = o;
  } else {
    if (tid < NBATCH) out[tid] = 0.f;
  }
}

// ---- E precompute: E^T[t] fragments in main-loop register layout ----
// E^T = (128*Bmat) @ inp^T per t. Grid (T/TC, 2 batch-groups), 256 thr = 4 waves
// x 5 tiles. Lane packs its 4 f32 -> one uint2 at
// Efrag[(t*40 + bg*20 + nt)*64 + lane]  (512B fully-coalesced per wave-store).
__global__ __launch_bounds__(256, 2)
void emis_pack(const uint32_t* __restrict__ Bfr, const float* __restrict__ inp,
               uint2* __restrict__ Efrag) {
  __shared__ __attribute__((aligned(16))) _Float16 inH[2][16 * 136];
  int tc = blockIdx.x, bg = blockIdx.y, bbase = bg * 16;
  int tid = threadIdx.x, lane = tid & 63, w = tid >> 6;
  int gl = lane & 15, quad = lane >> 4;

  half8 bfB[5][4];
#pragma unroll
  for (int q = 0; q < 5; q++)
#pragma unroll
    for (int kt = 0; kt < 4; kt++)
      bfB[q][kt] = h8_from_u4(((const uint4*)Bfr)[((w * 5 + q) * 4 + kt) * 64 + lane]);
#pragma unroll
  for (int q = 0; q < 5; q++)
#pragma unroll
    for (int kt = 0; kt < 4; kt++) asm volatile("" : "+v"(bfB[q][kt]));

  int t0 = tc * TC;
#pragma unroll
  for (int s = 0; s < 4; s++) {
    int flat = tid + s * 256;
    int r = flat >> 6, c2 = flat & 63;
    float2 v; v.x = 0.f; v.y = 0.f;
    if (c2 < 63) v = *(const float2*)(inp + ((size_t)(bbase + r) * T_LEN + t0) * E_DIM + 2 * c2);
    *(uint32_t*)&inH[0][r * 136 + 2 * c2] = pk2(v.x, v.y);
  }
  float2 g[4];   // prefetch t0+1
#pragma unroll
  for (int s = 0; s < 4; s++) {
    int flat = tid + s * 256;
    int r = flat >> 6, c2 = flat & 63;
    g[s].x = 0.f; g[s].y = 0.f;
    if (c2 < 63) g[s] = *(const float2*)(inp + ((size_t)(bbase + r) * T_LEN + (t0 + 1)) * E_DIM + 2 * c2);
  }
  __syncthreads();

  for (int i = 0; i < TC; i++) {
    int cur = i & 1, t = t0 + i;
    floatx4 Ea[5];
#pragma unroll
    for (int q = 0; q < 5; q++) Ea[q] = (floatx4){0.f, 0.f, 0.f, 0.f};
#pragma unroll
    for (int kt = 0; kt < 4; kt++) {
      half8 af = h8_from_u4(*(const uint4*)&inH[cur][gl * 136 + kt * 32 + quad * 8]);
#pragma unroll
      for (int q = 0; q < 5; q++)
        Ea[q] = __builtin_amdgcn_mfma_f32_16x16x32_f16(bfB[q][kt], af, Ea[q], 0, 0, 0);
    }
    if (i < TC - 1) {
#pragma unroll
      for (int s = 0; s < 4; s++) {
        int flat = tid + s * 256;
        int r = flat >> 6, c2 = flat & 63;
        uint32_t pv = (c2 < 63) ? pk2(g[s].x, g[s].y) : 0u;
        *(uint32_t*)&inH[cur ^ 1][r * 136 + 2 * c2] = pv;
      }
      int tp = t0 + i + 2; if (tp > T_LEN - 1) tp = T_LEN - 1;
#pragma unroll
      for (int s = 0; s < 4; s++) {
        int flat = tid + s * 256;
        int r = flat >> 6, c2 = flat & 63;
        g[s].x = 0.f; g[s].y = 0.f;
        if (c2 < 63) g[s] = *(const float2*)(inp + ((size_t)(bbase + r) * T_LEN + tp) * E_DIM + 2 * c2);
      }
    }
#pragma unroll
    for (int q = 0; q < 5; q++) {
      uint2 o;
      o.x = pk2(Ea[q][0], Ea[q][1]);
      o.y = pk2(Ea[q][2], Ea[q][3]);
      Efrag[((size_t)t * 40 + bg * 20 + (w * 5 + q)) * 64 + lane] = o;
    }
    __syncthreads();
  }
}

// ---- fused recursion, round-9: fragment-linear QL (kills the ~10cyc/read tax) ----
// Round-6 diagnosis: conflicts/ds_read_b128 ~= 10 extra cycles in EVERY strided
// row layout tried (336/720B) -> reads run ~3x nominal; with 8 waves the LDS
// unit is the serial resource. Fix: store Q in MFMA B-FRAGMENT ORDER:
//   fragment block kt (1024B): consumer lane l's 16B at  kt*1024 + l*16
//     holding Q[k=kt*32+(l>>4)*8+j][n=l&15]  (j=0..7).
// Reads are LINEAR (lane*16) -> zero conflicts by construction (lanes 0..7
// cover all 32 banks exactly once). Writes: lane (gl,quad) owns the 8B granule
// of 4 states s0=(nt*16+quad*4) for batch gl -> byte =
//   (s0>>5)*1024 + ((((nt&1)<<1)|(quad>>1))*16 + gl)*16 + (quad&1)*8
// each 32-lane half covers all 32 banks exactly 2x (HW minimum, no extra).
// Structure otherwise identical to round 6 (verified): 8 waves, tile split
// 3/3/3/3/2/2/2/2 (SIMD-balanced), lockstep dual-stream, one barrier/pair-step.
__global__ __launch_bounds__(512, 2)
void hmm_fused7(const uint32_t* __restrict__ Apk, const uint2* __restrict__ Efrag,
                const float* __restrict__ Ivec, float* __restrict__ out) {
  __shared__ __attribute__((aligned(16))) _Float16 QL[2][2][5120]; // [stream][buf] frag-order
  __shared__ float zsl[2][16];
  int bg = blockIdx.y, bbase = bg * 16;
  int cc0 = blockIdx.x * 2, cc1 = cc0 + 1;
  int tid = threadIdx.x, lane = tid & 63, w = tid >> 6;
  int gl = lane & 15, quad = lane >> 4;
  int base = (w < 4) ? 3 * w : 12 + 2 * (w - 4);   // first n-tile owned by this wave
  int cnt  = (w < 4) ? 3 : 2;                      // tiles owned (SIMD-pair = 5)

  half8 bfA[3][10];
#pragma unroll
  for (int q = 0; q < 3; q++)
#pragma unroll
    for (int kt = 0; kt < 10; kt++)
      bfA[q][kt] = (q < cnt)
        ? h8_from_u4(((const uint4*)Apk)[((base + q) * 10 + kt) * 64 + lane])
        : h8_zero();
#pragma unroll
  for (int q = 0; q < 3; q++)
#pragma unroll
    for (int kt = 0; kt < 10; kt++) asm volatile("" : "+v"(bfA[q][kt]));

  // P state-major: lane holds states (base+q)*16 + quad*4 + r for batch gl
  floatx4 Pa[2][3];
#pragma unroll
  for (int q = 0; q < 3; q++)
#pragma unroll
    for (int r = 0; r < 4; r++) {
      int st = (base + q) * 16 + quad * 4 + r;
      bool ok = (q < cnt) && (st < S_DIM);
      Pa[0][q][r] = ok ? ((cc0 == 0) ? Ivec[st] : 1.0f) : 0.f;
      Pa[1][q][r] = ok ? 1.0f : 0.f;
    }
  if (tid < 32) zsl[tid >> 4][tid & 15] = 0.f;

  int tfX = cc0 * CHL - WARM + 1;   // -5 for cc0==0 (garbage warm, reset at IW)
  int tfY = cc1 * CHL - WARM + 1;
  int tlX = tfX + NSTEP - 1, tlY = tfY + NSTEP - 1;

  // per-tile QL write byte offsets (fragment-order scatter; see header comment)
  int wboff[3];
#pragma unroll
  for (int q = 0; q < 3; q++) {
    int nt = base + q;
    int s0 = nt * 16 + quad * 4;
    wboff[q] = (s0 >> 5) * 1024 + (((((nt & 1) << 1) | (quad >> 1)) * 16 + gl) << 4)
             + ((quad & 1) << 3);
  }

  size_t ebase = (size_t)bg * 1280 + (size_t)base * 64 + lane;
  uint2 EA[2][3], EB[2][3];
  EA[0][2] = EA[1][2] = EB[0][2] = EB[1][2] = (uint2){0u, 0u};
  {
    int ta0 = tfX - 1; if (ta0 < 0) ta0 = 0;
    int tb0 = tfX;     if (tb0 < 0) tb0 = 0;
    int ta1 = tfY - 1; if (ta1 < 0) ta1 = 0;
    int tb1 = tfY;
#pragma unroll
    for (int q = 0; q < 3; q++)
      if (q < cnt) {
        EA[0][q] = Efrag[(size_t)ta0 * 2560 + ebase + (size_t)q * 64];
        EB[0][q] = Efrag[(size_t)tb0 * 2560 + ebase + (size_t)q * 64];
        EA[1][q] = Efrag[(size_t)ta1 * 2560 + ebase + (size_t)q * 64];
        EB[1][q] = Efrag[(size_t)tb1 * 2560 + ebase + (size_t)q * 64];
      }
  }

  float llw0 = 0.f, llw1 = 0.f;

  auto step = [&](uint2 (&E)[2][3], int ii) {
    int cur = ii & 1;
    // ---- phase a: Q = P (.) E, both streams (registers only)
    float qv[2][3][4];
#pragma unroll
    for (int s = 0; s < 2; s++)
#pragma unroll
      for (int q = 0; q < 3; q++)
        if (q < cnt) {
          half4 ev = h4_from_u2(E[s][q]);
#pragma unroll
          for (int r = 0; r < 4; r++) qv[s][q][r] = Pa[s][q][r] * (float)ev[r];
        }
    // checkpoints: z[b] = sum_s Q[s][b]
    if (ii == IW || ii == NSTEP) {
#pragma unroll
      for (int s = 0; s < 2; s++) {
        float z = 0.f;
#pragma unroll
        for (int q = 0; q < 3; q++)
          if (q < cnt) z += (qv[s][q][0] + qv[s][q][1]) + (qv[s][q][2] + qv[s][q][3]);
        z += __shfl_xor(z, 16); z += __shfl_xor(z, 32);
        if (lane < 16) atomicAdd(&zsl[s][lane], z);
      }
    }
    // write Q -> QL[s][cur] in fragment order: one b64 per tile, conflict-free
#pragma unroll
    for (int s = 0; s < 2; s++)
#pragma unroll
      for (int q = 0; q < 3; q++)
        if (q < cnt) {
          uint2 o;
          o.x = pk2(qv[s][q][0], qv[s][q][1]);
          o.y = pk2(qv[s][q][2], qv[s][q][3]);
          *(uint2*)((char*)&QL[s][cur][0] + wboff[q]) = o;
        }
    __syncthreads();   // the ONLY barrier per pair-step
    if (ii == IW) {
      if (tid < 16) {
        llw0 = cc0 ? logf(zsl[0][tid]) : 0.f;    // cc0==0: garbage warm, llw stays 0
        llw1 = logf(zsl[1][tid]);
        zsl[0][tid] = 0.f; zsl[1][tid] = 0.f;
      }
    }
    if (ii == NSTEP) {
      if (tid < 16) {
        float v = (logf(zsl[0][tid]) - llw0) + (logf(zsl[1][tid]) - llw1)
                  - 2.0f * (float)CHL * LN128;   // CHL accounted x128 steps per stream
        atomicAdd(&out[bbase + tid], v);
      }
      return;
    }
    // ---- phase b: E prefetch first (latency hides under MFMA/LDS below)
    {
      int tpX = tfX + ii + 1; if (tpX < 0) tpX = 0; if (tpX > tlX) tpX = tlX;
      int tpY = tfY + ii + 1; if (tpY < 0) tpY = 0; if (tpY > tlY) tpY = tlY;
#pragma unroll
      for (int q = 0; q < 3; q++)
        if (q < cnt) {
          E[0][q] = Efrag[(size_t)tpX * 2560 + ebase + (size_t)q * 64];
          E[1][q] = Efrag[(size_t)tpY * 2560 + ebase + (size_t)q * 64];
        }
    }
    // P^T = A^T @ Q^T, both streams: LINEAR ds_read_b128 (kt*1024 + lane*16)
    floatx4 aX[3], aY[3];
#pragma unroll
    for (int q = 0; q < 3; q++) { aX[q] = (floatx4){0.f,0.f,0.f,0.f}; aY[q] = aX[q]; }
#pragma unroll
    for (int kt = 0; kt < 10; kt++) {
      half8 q0 = h8_from_u4(*(const uint4*)((const char*)&QL[0][cur][0] + kt * 1024 + lane * 16));
      half8 q1 = h8_from_u4(*(const uint4*)((const char*)&QL[1][cur][0] + kt * 1024 + lane * 16));
#pragma unroll
      for (int q = 0; q < 3; q++)
        if (q < cnt) {
          aX[q] = __builtin_amdgcn_mfma_f32_16x16x32_f16(bfA[q][kt], q0, aX[q], 0, 0, 0);
          aY[q] = __builtin_amdgcn_mfma_f32_16x16x32_f16(bfA[q][kt], q1, aY[q], 0, 0, 0);
        }
    }
#pragma unroll
    for (int q = 0; q < 3; q++) { Pa[0][q] = aX[q]; Pa[1][q] = aY[q]; }
    if (ii == IW && cc0 == 0) {
      // exact restart of chunk 0 at t=0 (its next phase-a uses E(0))
#pragma unroll
      for (int q = 0; q < 3; q++)
#pragma unroll
        for (int r = 0; r < 4; r++) {
          int st = (base + q) * 16 + quad * 4 + r;
          Pa[0][q][r] = ((q < cnt) && st < S_DIM) ? Ivec[st] : 0.f;
        }
    }
  };

  // NSTEP odd -> even number of steps; EA/EB statically selected
  for (int i = 0; i <= NSTEP; i += 2) {
    step(EA, i);
    step(EB, i + 1);
  }
}

// ---- fallback (inp-direct, no Efrag workspace) ----
__global__ __launch_bounds__(640, 3)
void hmm_fused(const uint32_t* __restrict__ Apk,
               const uint32_t* __restrict__ Bfr,
               const float* __restrict__ inp,
               const float* __restrict__ Ivec,
               float* __restrict__ out) {
  __shared__ __attribute__((aligned(16))) _Float16 inH[2][16 * 136];
  __shared__ __attribute__((aligned(16))) _Float16 QLf[2][16 * 336];
  __shared__ float zslot[16];
  int c = blockIdx.x, bbase = blockIdx.y * 16;
  int tid = threadIdx.x, lane = tid & 63, w = tid >> 6;
  int gl = lane & 15, quad = lane >> 4;

  half8 bfA[2][10], bfB[2][4];
#pragma unroll
  for (int q = 0; q < 2; q++) {
#pragma unroll
    for (int kt = 0; kt < 10; kt++)
      bfA[q][kt] = h8_from_u4(((const uint4*)Apk)[((w * 2 + q) * 10 + kt) * 64 + lane]);
#pragma unroll
    for (int kt = 0; kt < 4; kt++)
      bfB[q][kt] = h8_from_u4(((const uint4*)Bfr)[((w * 2 + q) * 4 + kt) * 64 + lane]);
  }
#pragma unroll
  for (int q = 0; q < 2; q++) {
#pragma unroll
    for (int kt = 0; kt < 10; kt++) asm volatile("" : "+v"(bfA[q][kt]));
#pragma unroll
    for (int kt = 0; kt < 4; kt++)  asm volatile("" : "+v"(bfB[q][kt]));
  }

  float Pa[2][4];
#pragma unroll
  for (int q = 0; q < 2; q++) {
    int n = (w * 2 + q) * 16 + gl;
    float v = (n < S_DIM) ? (c == 0 ? Ivec[n] : 1.0f) : 0.f;
#pragma unroll
    for (int r = 0; r < 4; r++) Pa[q][r] = v;
  }
  if (tid < 16) zslot[tid] = 0.f;

  int t_first = (c == 0) ? 1 : (c * CHL - WARM + 1);
  int nstep   = (c == 0) ? (CHL - 1) : (CHL + WARM - 1);
  int iw      = (c == 0) ? -1 : (WARM - 1);
  int t_last  = t_first - 1 + nstep;

  {
    int t0 = t_first - 1;
#pragma unroll
    for (int s = 0; s < 2; s++) {
      int flat = tid + s * 640;
      if (flat < 1024) {
        int r = flat >> 6, c2 = flat & 63;
        float2 v; v.x = 0.f; v.y = 0.f;
        if (c2 < 63) v = *(const float2*)(inp + ((size_t)(bbase + r) * T_LEN + t0) * E_DIM + 2 * c2);
        *(uint32_t*)&inH[0][r * 136 + 2 * c2] = pk2(v.x, v.y);
      }
    }
  }
  float2 g[2];
#pragma unroll
  for (int s = 0; s < 2; s++) {
    int flat = tid + s * 640;
    g[s].x = 0.f; g[s].y = 0.f;
    if (flat < 1024) {
      int r = flat >> 6, c2 = flat & 63;
      if (c2 < 63) g[s] = *(const float2*)(inp + ((size_t)(bbase + r) * T_LEN + t_first) * E_DIM + 2 * c2);
    }
  }
  float llw = 0.f;
  __syncthreads();

  for (int i = 0; i <= nstep; i++) {
    int cur = i & 1, nxt = cur ^ 1;
    floatx4 Ea0 = (floatx4){0.f, 0.f, 0.f, 0.f};
    floatx4 Ea1 = (floatx4){0.f, 0.f, 0.f, 0.f};
#pragma unroll
    for (int kt = 0; kt < 4; kt++) {
      half8 af = h8_from_u4(*(const uint4*)&inH[cur][gl * 136 + kt * 32 + quad * 8]);
      Ea0 = __builtin_amdgcn_mfma_f32_16x16x32_f16(af, bfB[0][kt], Ea0, 0, 0, 0);
      Ea1 = __builtin_amdgcn_mfma_f32_16x16x32_f16(af, bfB[1][kt], Ea1, 0, 0, 0);
    }
    float qv[2][4];
#pragma unroll
    for (int r = 0; r < 4; r++) { qv[0][r] = Pa[0][r] * Ea0[r]; qv[1][r] = Pa[1][r] * Ea1[r]; }
    if (i == iw || i == nstep) {
      float s0 = qv[0][0] + qv[1][0], s1 = qv[0][1] + qv[1][1];
      float s2 = qv[0][2] + qv[1][2], s3 = qv[0][3] + qv[1][3];
#pragma unroll
      for (int off = 1; off <= 8; off <<= 1) {
        s0 += __shfl_xor(s0, off); s1 += __shfl_xor(s1, off);
        s2 += __shfl_xor(s2, off); s3 += __shfl_xor(s3, off);
      }
      if (gl == 0) {
        atomicAdd(&zslot[quad * 4 + 0], s0);
        atomicAdd(&zslot[quad * 4 + 1], s1);
        atomicAdd(&zslot[quad * 4 + 2], s2);
        atomicAdd(&zslot[quad * 4 + 3], s3);
      }
    }
#pragma unroll
    for (int q = 0; q < 2; q++) {
      int k = (w * 2 + q) * 16 + gl;
#pragma unroll
      for (int r = 0; r < 4; r++)
        QLf[cur][(quad * 4 + r) * 336 + k] = (_Float16)qv[q][r];
    }
    if (i < nstep) {
#pragma unroll
      for (int s = 0; s < 2; s++) {
        int flat = tid + s * 640;
        if (flat < 1024) {
          int r = flat >> 6, c2 = flat & 63;
          uint32_t pv = (c2 < 63) ? pk2(g[s].x, g[s].y) : 0u;
          *(uint32_t*)&inH[nxt][r * 136 + 2 * c2] = pv;
        }
      }
    }
    __syncthreads();
    if (i == iw && tid < 16) { llw = logf(zslot[tid]); zslot[tid] = 0.f; }
    if (i == nstep) {
      if (tid < 16) {
        float lle = logf(zslot[tid]);
        atomicAdd(&out[bbase + tid], lle - llw - (float)CHL * LN128);
      }
      break;
    }
    {
      int tp = t_first + i + 1; if (tp > t_last) tp = t_last;
#pragma unroll
      for (int s = 0; s < 2; s++) {
        int flat = tid + s * 640;
        g[s].x = 0.f; g[s].y = 0.f;
        if (flat < 1024) {
          int r = flat >> 6, c2 = flat & 63;
          if (c2 < 63) g[s] = *(const float2*)(inp + ((size_t)(bbase + r) * T_LEN + tp) * E_DIM + 2 * c2);
        }
      }
    }
    floatx4 acc0 = (floatx4){0.f, 0.f, 0.f, 0.f};
    floatx4 acc1 = (floatx4){0.f, 0.f, 0.f, 0.f};
#pragma unroll
    for (int kt = 0; kt < 10; kt++) {
      half8 afv = h8_from_u4(*(const uint4*)&QLf[cur][gl * 336 + kt * 32 + quad * 8]);
      acc0 = __builtin_amdgcn_mfma_f32_16x16x32_f16(afv, bfA[0][kt], acc0, 0, 0, 0);
      acc1 = __builtin_amdgcn_mfma_f32_16x16x32_f16(afv, bfA[1][kt], acc1, 0, 0, 0);
    }
#pragma unroll
    for (int r = 0; r < 4; r++) { Pa[0][r] = acc0[r]; Pa[1][r] = acc1[r]; }
  }
}

extern "C" void kernel_launch(void* const* d_in, const int* in_sizes, int n_in,
                              void* d_out, int out_size, void* d_ws, size_t ws_size,
                              hipStream_t stream) {
  const float* inp = (const float*)d_in[0];   // [32,4096,126]
  const float* A   = (const float*)d_in[1];   // [308,308]
  const float* Bm  = (const float*)d_in[2];   // [308,126]
  const float* Iv  = (const float*)d_in[3];   // [308]
  float* out = (float*)d_out;                 // [32]

  uint8_t* ws = (uint8_t*)d_ws;
  uint32_t* Apk = (uint32_t*)(ws);                 // 200 KiB
  uint32_t* Bfr = (uint32_t*)(ws + (256u << 10));  // 80 KiB
  const size_t EOFF   = (size_t)384 << 10;
  const size_t EBYTES = (size_t)T_LEN * 40 * 64 * sizeof(uint2);  // 80 MiB

  hipLaunchKernelGGL(init_pack, dim3(71), dim3(256), 0, stream, A, Bm, Apk, Bfr, out);
  if (ws_size >= EOFF + EBYTES) {
    uint2* Efrag = (uint2*)(ws + EOFF);
    hipLaunchKernelGGL(emis_pack, dim3(T_LEN / TC, 2), dim3(256), 0, stream, Bfr, inp, Efrag);
    hipLaunchKernelGGL(hmm_fused7, dim3(NCH / 2, NBATCH / 16), dim3(512), 0, stream,
                       Apk, Efrag, Iv, out);
  } else {
    hipLaunchKernelGGL(hmm_fused, dim3(NCH, NBATCH / 16), dim3(640), 0, stream,
                       Apk, Bfr, inp, Iv, out);
  }
}